// Round 15
// baseline (2576.971 us; speedup 1.0000x reference)
//
#include <hip/hip_runtime.h>
#include <hip/hip_bf16.h>

#define N_NODES 100000
#define N_EDGES 3200000
#define F_IN    128
#define H1F     64
#define H2F     32
#define NCLS    32
#define NTILES (N_NODES / 16)                                   // 6250 exact
#define NCNT   (N_EDGES / 4 / 256)                              // 3125 count blocks
#define XPAD 132                                                // 128+4 shorts: LDS de-alias
#define NB    1563                                              // buckets of 64 dst nodes
#define BCAP  2560                                              // edges per bucket (λ=2048+11σ)
#define OVCAP 65536

typedef __attribute__((ext_vector_type(8))) short bf16x8;
typedef __attribute__((ext_vector_type(4))) float f32x4;

static __device__ __forceinline__ float b2f(__hip_bfloat16 v) {
    return __bfloat162float(v);
}
static __device__ __forceinline__ float us2f(unsigned short u) {
    return __uint_as_float(((unsigned)u) << 16);
}
static __device__ __forceinline__ unsigned short f2us(float f) {
    __hip_bfloat16 h = __float2bfloat16(f);
    return *(unsigned short*)&h;
}
static __device__ __forceinline__ float ld(const void* p, size_t i, int isbf) {
    return isbf ? b2f(((const __hip_bfloat16*)p)[i]) : ((const float*)p)[i];
}
static __device__ __forceinline__ float dinvf(int dg) {
    return rsqrtf((float)dg + 1.0f);                   // +1 self-loop
}

// flags[0] = edge_index is int64 ; flags[1] = float tensors are bf16

__global__ void k_detect(const void* xbuf, const void* eibuf, int* flags) {
    if (threadIdx.x != 0 || blockIdx.x != 0) return;
    const unsigned* ew = (const unsigned*)eibuf;
    int z = 0;
    for (int k = 0; k < 256; ++k) z += (ew[2 * k + 1] == 0u) ? 1 : 0;
    flags[0] = (z >= 200) ? 1 : 0;
    const unsigned* xw = (const unsigned*)xbuf;
    int inr = 0;
    for (int k = 0; k < 256; ++k) {
        unsigned fb = (xw[k] & 0xFFFFu) << 16;
        float a = fabsf(__uint_as_float(fb));
        inr += (a >= 1e-4f && a <= 20.0f) ? 1 : 0;
    }
    flags[1] = (inr >= 160) ? 1 : 0;
}

// ---------- pack W1 into MFMA B-fragment order + init bucket cursors ----------
__global__ void k_packW1(const unsigned short* __restrict__ W1,
                         unsigned short* __restrict__ W1p, int* __restrict__ cursor) {
    int t = blockIdx.x * blockDim.x + threadIdx.x;      // 8192 threads
    if (t < NB) cursor[t] = t * BCAP;
    if (t >= F_IN * H1F) return;
    int j    = t & 7;
    int lane = (t >> 3) & 63;
    int fg   = (t >> 9) & 3;
    int kc   = t >> 11;
    int quad = lane >> 4, col = lane & 15;
    W1p[t] = W1[(kc * 32 + quad * 8 + j) * H1F + fg * 16 + col];
}

// ---------------- FUSED front-end ----------------
// blk%3==0 -> histogram + dense bucket append (3125 blocks)
// else     -> gemm1 MFMA tile block (6250 blocks)
__global__ void __launch_bounds__(256)
k_front(const void* __restrict__ x, const void* __restrict__ W1,
        const unsigned short* __restrict__ W1p, const int* __restrict__ ei,
        int* __restrict__ deg, int* __restrict__ cursor, int* __restrict__ bkt,
        int* __restrict__ novf, int2* __restrict__ ov,
        unsigned short* __restrict__ h1, const int* __restrict__ flags) {
    __shared__ unsigned short w1s[F_IN * H1F];          // 16 KB
    __shared__ unsigned short xs[16 * XPAD];            // 4.2 KB
    int blk = blockIdx.x, tid = threadIdx.x;

    if (blk % 3 == 0) {
        int t = (blk / 3) * 256 + tid;
        int e0 = t * 4;
        if (e0 >= N_EDGES) return;
        int s[4], d[4];
        if (flags[0]) {
            const int4* ps = (const int4*)(ei + 2 * (size_t)e0);
            int4 a = ps[0], b = ps[1];
            s[0] = a.x; s[1] = a.z; s[2] = b.x; s[3] = b.z;
            const int4* pd = (const int4*)(ei + 2 * (size_t)(N_EDGES + e0));
            int4 c = pd[0], g = pd[1];
            d[0] = c.x; d[1] = c.z; d[2] = g.x; d[3] = g.z;
        } else {
            int4 a = *(const int4*)(ei + (size_t)e0);
            s[0] = a.x; s[1] = a.y; s[2] = a.z; s[3] = a.w;
            int4 c = *(const int4*)(ei + (size_t)N_EDGES + e0);
            d[0] = c.x; d[1] = c.y; d[2] = c.z; d[3] = c.w;
        }
#pragma unroll
        for (int j = 0; j < 4; ++j) {
            if ((unsigned)d[j] < N_NODES) {
                atomicAdd(&deg[d[j]], 1);
                if ((unsigned)s[j] < N_NODES) {
                    int b    = d[j] >> 6;
                    int dlow = d[j] & 63;
                    int pos  = atomicAdd(&cursor[b], 1);
                    int idx  = pos - b * BCAP;
                    if (idx < BCAP) {
                        bkt[pos] = s[j] | (dlow << 17);   // s<2^17, dlow<2^6
                    } else {
                        int o = atomicAdd(novf, 1);
                        if (o < OVCAP) ov[o] = make_int2(d[j], s[j]);
                    }
                }
            }
        }
        return;
    }

    // -------- gemm1 MFMA tile (unchanged, verified rounds 12-14) --------
    int tile = blk - blk / 3 - 1;                       // 0..6249 exact bijection
    int isbf = flags[1];
    if (isbf) {
        const uint4* src = (const uint4*)W1p;
        uint4*       dst = (uint4*)w1s;
#pragma unroll
        for (int k = 0; k < 4; ++k) dst[tid + k * 256] = src[tid + k * 256];
        const short* xp = (const short*)x + (size_t)tile * 16 * F_IN;
        int r = tid >> 4, c = tid & 15;
        *(bf16x8*)(xs + r * XPAD + c * 8) = *(const bf16x8*)(xp + tid * 8);
    }
    __syncthreads();

    int wave = tid >> 6, lane = tid & 63;
    int col = lane & 15, quad = lane >> 4;
    int fg = wave;

    if (isbf) {
        bf16x8 afr[4];
#pragma unroll
        for (int kc = 0; kc < 4; ++kc)
            afr[kc] = *(const bf16x8*)(xs + col * XPAD + kc * 32 + quad * 8);
        f32x4 acc;
#pragma unroll
        for (int r = 0; r < 4; ++r) acc[r] = 0.f;
#pragma unroll
        for (int kc = 0; kc < 4; ++kc) {
            bf16x8 bfr = *(const bf16x8*)(w1s + (((kc * 4 + fg) * 64 + lane) * 8));
            acc = __builtin_amdgcn_mfma_f32_16x16x32_bf16(afr[kc], bfr, acc, 0, 0, 0);
        }
#pragma unroll
        for (int r = 0; r < 4; ++r)
            h1[(size_t)(tile * 16 + quad * 4 + r) * H1F + fg * 16 + col] = f2us(acc[r]);
    } else {
        const float* wfp = (const float*)W1;
        for (int i = 0; i < 4; ++i) {
            int n = tile * 16 + wave * 4 + i;
            const float2* xr = (const float2*)((const float*)x + (size_t)n * F_IN);
            float2 my = xr[lane];
            float acc = 0.f;
#pragma unroll 16
            for (int k = 0; k < 64; ++k) {
                float x0 = __shfl(my.x, k, 64);
                float x1 = __shfl(my.y, k, 64);
                acc += x0 * wfp[(2 * k) * H1F + lane];
                acc += x1 * wfp[(2 * k + 1) * H1F + lane];
            }
            h1[(size_t)n * H1F + lane] = f2us(acc);
        }
    }
}

// ---------------- agg1 + bias/ReLU + GEMM2 ; block = 1 bucket (64 dst nodes) ----------------
__global__ void __launch_bounds__(256)
k_agg1gemm2(const unsigned short* __restrict__ h1, const int* __restrict__ deg,
            const int* __restrict__ cursor, const int* __restrict__ bkt,
            const int* __restrict__ novf, const int2* __restrict__ ov,
            const void* __restrict__ b1, const void* __restrict__ W2,
            unsigned short* __restrict__ h2, const int* __restrict__ flags) {
    __shared__ float agg[64 * H1F];                     // 16 KB
    int b = blockIdx.x, tid = threadIdx.x;
    int wave = tid >> 6, lane = tid & 63;
    int nbase = b * 64;
    // zero accumulator
#pragma unroll
    for (int k = 0; k < 16; ++k) agg[tid + k * 256] = 0.f;
    __syncthreads();

    int cnt = cursor[b] - b * BCAP;
    cnt = cnt < BCAP ? cnt : BCAP;
    const int* base = bkt + (size_t)b * BCAP;
    // each wave owns a contiguous chunk; 4-deep unrolled gather->LDS-accumulate
    int chunk = (cnt + 3) >> 2;
    int beg = wave * chunk, end = min(beg + chunk, cnt);
    int i = beg;
    for (; i + 3 < end; i += 4) {
        int p0 = base[i], p1 = base[i + 1], p2 = base[i + 2], p3 = base[i + 3];
        int s0 = p0 & 0x1FFFF, s1 = p1 & 0x1FFFF, s2 = p2 & 0x1FFFF, s3 = p3 & 0x1FFFF;
        float w0 = dinvf(deg[s0]), w1 = dinvf(deg[s1]);
        float w2 = dinvf(deg[s2]), w3 = dinvf(deg[s3]);
        float v0 = us2f(h1[(size_t)s0 * H1F + lane]);
        float v1 = us2f(h1[(size_t)s1 * H1F + lane]);
        float v2 = us2f(h1[(size_t)s2 * H1F + lane]);
        float v3 = us2f(h1[(size_t)s3 * H1F + lane]);
        atomicAdd(&agg[(p0 >> 17) * H1F + lane], w0 * v0);
        atomicAdd(&agg[(p1 >> 17) * H1F + lane], w1 * v1);
        atomicAdd(&agg[(p2 >> 17) * H1F + lane], w2 * v2);
        atomicAdd(&agg[(p3 >> 17) * H1F + lane], w3 * v3);
    }
    for (; i < end; ++i) {
        int p = base[i];
        int s = p & 0x1FFFF;
        atomicAdd(&agg[(p >> 17) * H1F + lane],
                  dinvf(deg[s]) * us2f(h1[(size_t)s * H1F + lane]));
    }
    // overflow replay (wave 0 only; normally empty)
    if (wave == 0) {
        int nov = *novf; nov = nov < OVCAP ? nov : OVCAP;
        for (int k = 0; k < nov; ++k) {
            int2 p = ov[k];
            if (p.x >= nbase && p.x < nbase + 64)
                atomicAdd(&agg[(p.x - nbase) * H1F + lane],
                          dinvf(deg[p.y]) * us2f(h1[(size_t)p.y * H1F + lane]));
        }
    }
    __syncthreads();

    // per-node: bias+ReLU+GEMM2 (16 nodes per wave)
    int isbf = flags[1];
    float bv = isbf ? b2f(((const __hip_bfloat16*)b1)[lane]) : ((const float*)b1)[lane];
    int f = lane & 31, h = lane >> 5;
    for (int k = 0; k < 16; ++k) {
        int nlow = wave * 16 + k;
        int n = nbase + nlow;
        if (n >= N_NODES) break;
        float dn = dinvf(deg[n]);
        float self = us2f(h1[(size_t)n * H1F + lane]);
        float v = fmaxf(dn * (dn * self + agg[nlow * H1F + lane]) + bv, 0.f);
        float part = 0.f;
        if (isbf) {
            const __hip_bfloat16* w = (const __hip_bfloat16*)W2;
#pragma unroll
            for (int j = 0; j < 32; ++j) {
                int kk = h * 32 + j;
                part += __shfl(v, kk, 64) * b2f(w[kk * H2F + f]);
            }
        } else {
            const float* w = (const float*)W2;
#pragma unroll
            for (int j = 0; j < 32; ++j) {
                int kk = h * 32 + j;
                part += __shfl(v, kk, 64) * w[kk * H2F + f];
            }
        }
        part += __shfl(part, lane ^ 32, 64);
        if (h == 0) h2[(size_t)n * H2F + f] = f2us(part);
    }
}

// ---------------- agg2 + final MLP ; block = 1 bucket (64 dst nodes) ----------------
__global__ void __launch_bounds__(256)
GCN_51737176048479_kernel(const unsigned short* __restrict__ h2,
                          const int* __restrict__ deg,
                          const int* __restrict__ cursor, const int* __restrict__ bkt,
                          const int* __restrict__ novf, const int2* __restrict__ ov,
                          const void* __restrict__ b2v, const void* __restrict__ Wf,
                          const void* __restrict__ bfv, const void* __restrict__ Wo,
                          const void* __restrict__ bov, void* __restrict__ out,
                          const int* __restrict__ flags) {
    __shared__ float agg[64 * H2F];                     // 8 KB
    int b = blockIdx.x, tid = threadIdx.x;
    int nbase = b * 64;
    int f = tid & 31, hw = tid >> 5;                    // 8 half-waves
#pragma unroll
    for (int k = 0; k < 8; ++k) agg[tid + k * 256] = 0.f;
    __syncthreads();

    int cnt = cursor[b] - b * BCAP;
    cnt = cnt < BCAP ? cnt : BCAP;
    const int* base = bkt + (size_t)b * BCAP;
    int chunk = (cnt + 7) >> 3;
    int beg = hw * chunk, end = min(beg + chunk, cnt);
    int i = beg;
    for (; i + 3 < end; i += 4) {
        int p0 = base[i], p1 = base[i + 1], p2 = base[i + 2], p3 = base[i + 3];
        int s0 = p0 & 0x1FFFF, s1 = p1 & 0x1FFFF, s2 = p2 & 0x1FFFF, s3 = p3 & 0x1FFFF;
        float w0 = dinvf(deg[s0]), w1 = dinvf(deg[s1]);
        float w2 = dinvf(deg[s2]), w3 = dinvf(deg[s3]);
        float v0 = us2f(h2[(size_t)s0 * H2F + f]);
        float v1 = us2f(h2[(size_t)s1 * H2F + f]);
        float v2 = us2f(h2[(size_t)s2 * H2F + f]);
        float v3 = us2f(h2[(size_t)s3 * H2F + f]);
        atomicAdd(&agg[(p0 >> 17) * H2F + f], w0 * v0);
        atomicAdd(&agg[(p1 >> 17) * H2F + f], w1 * v1);
        atomicAdd(&agg[(p2 >> 17) * H2F + f], w2 * v2);
        atomicAdd(&agg[(p3 >> 17) * H2F + f], w3 * v3);
    }
    for (; i < end; ++i) {
        int p = base[i];
        int s = p & 0x1FFFF;
        atomicAdd(&agg[(p >> 17) * H2F + f],
                  dinvf(deg[s]) * us2f(h2[(size_t)s * H2F + f]));
    }
    if (hw == 0) {                                      // overflow replay, half-wave 0
        int nov = *novf; nov = nov < OVCAP ? nov : OVCAP;
        for (int k = 0; k < nov; ++k) {
            int2 p = ov[k];
            if (p.x >= nbase && p.x < nbase + 64)
                atomicAdd(&agg[(p.x - nbase) * H2F + f],
                          dinvf(deg[p.y]) * us2f(h2[(size_t)p.y * H2F + f]));
        }
    }
    __syncthreads();

    int isbf = flags[1];
    for (int k = 0; k < 8; ++k) {                       // 8 nodes per half-wave
        int nlow = hw * 8 + k;
        int n = nbase + nlow;
        if (n >= N_NODES) break;
        float dn = dinvf(deg[n]);
        float self = us2f(h2[(size_t)n * H2F + f]);
        float ar = dn * (dn * self + agg[nlow * H2F + f]) + ld(b2v, f, isbf);
        float acc1 = 0.f;
#pragma unroll
        for (int j = 0; j < H2F; ++j)
            acc1 += __shfl(ar, j, 32) * ld(Wf, (size_t)j * H2F + f, isbf);
        float u = fmaxf(acc1 + ld(bfv, f, isbf), 0.f);
        float acc2 = 0.f;
#pragma unroll
        for (int j = 0; j < H2F; ++j)
            acc2 += __shfl(u, j, 32) * ld(Wo, (size_t)j * NCLS + f, isbf);
        float r = acc2 + ld(bov, f, isbf);
        size_t oi = (size_t)n * NCLS + f;
        if (isbf) ((__hip_bfloat16*)out)[oi] = __float2bfloat16(r);
        else      ((float*)out)[oi] = r;
    }
}

extern "C" void kernel_launch(void* const* d_in, const int* in_sizes, int n_in,
                              void* d_out, int out_size, void* d_ws, size_t ws_size,
                              hipStream_t stream) {
    const void* x  = d_in[0];
    const int*  ei = (const int*)d_in[1];
    const void* W1 = d_in[2];
    const void* b1 = d_in[3];
    const void* W2 = d_in[4];
    const void* b2 = d_in[5];
    const void* Wf = d_in[6];
    const void* bf = d_in[7];
    const void* Wo = d_in[8];
    const void* bo = d_in[9];

    // workspace (peak ~38 MB):
    //  deg @0 (400000) | novf @400000 | flags @480K | ov @512K (512KB) | cursor @1M (6.3K)
    //  W1p @1.5M (16K) | bkt @2M (16.0MB) | h1 @18.5M (12.8MB) | h2 @31.5M (6.4MB)
    char* ws = (char*)d_ws;
    int*            deg    = (int*)  (ws + 0);
    int*            novf   = (int*)  (ws + 400000);
    int*            flags  = (int*)  (ws + (480u << 10));
    int2*           ov     = (int2*) (ws + (512u << 10));
    int*            cursor = (int*)  (ws + (1024u << 10));
    unsigned short* W1p    = (unsigned short*)(ws + (1536u << 10));
    int*            bkt    = (int*)  (ws + (2048u << 10));
    unsigned short* h1     = (unsigned short*)(ws + (18944u << 10));
    unsigned short* h2     = (unsigned short*)(ws + (32256u << 10));

    const int B = 256;

    k_detect<<<1, 64, 0, stream>>>(x, ei, flags);
    hipMemsetAsync(deg, 0, 400004, stream);             // deg + novf
    k_packW1<<<(F_IN * H1F + B - 1) / B, B, 0, stream>>>((const unsigned short*)W1,
                                                         W1p, cursor);

    // fused gemm1 + histogram + dense bucket append
    k_front<<<NTILES + NCNT, B, 0, stream>>>(x, W1, W1p, ei, deg, cursor, bkt,
                                             novf, ov, h1, flags);

    k_agg1gemm2<<<NB, B, 0, stream>>>(h1, deg, cursor, bkt, novf, ov, b1, W2, h2, flags);
    GCN_51737176048479_kernel<<<NB, B, 0, stream>>>(h2, deg, cursor, bkt, novf, ov,
                                                    b2, Wf, bf, Wo, bo, d_out, flags);
}